// Round 1
// baseline (533.005 us; speedup 1.0000x reference)
//
#include <hip/hip_runtime.h>
#include <cstddef>

#define N_IMG 8
#define B_BOX 1000
#define N_CLS 80
#define C1    81          // classes + background column
#define K_MAX 100
#define CAND  (N_CLS * K_MAX)   // 8000 candidates per image
#define NEGV  (-1.0e10f)

// Stable block-wide argmax over per-thread (v, idx) candidates.
// Tie rule: lower index wins (matches jnp.argmax first-occurrence).
__device__ __forceinline__ void blockArgmax(float &v, int &idx,
                                            float* redV, int* redI, int tid)
{
    const int lane = tid & 63, wave = tid >> 6;
    #pragma unroll
    for (int off = 32; off > 0; off >>= 1) {
        float ov = __shfl_down(v, off);
        int   oi = __shfl_down(idx, off);
        if (ov > v || (ov == v && oi < idx)) { v = ov; idx = oi; }
    }
    if (lane == 0) { redV[wave] = v; redI[wave] = idx; }
    __syncthreads();
    if (tid == 0) {
        float bv = redV[0]; int bi = redI[0];
        #pragma unroll
        for (int w = 1; w < 4; w++) {
            if (redV[w] > bv || (redV[w] == bv && redI[w] < bi)) {
                bv = redV[w]; bi = redI[w];
            }
        }
        redV[0] = bv; redI[0] = bi;
    }
    __syncthreads();
    v = redV[0]; idx = redI[0];
}

// One block per (image n, class c): decode boxes, sequential NMS, emit
// up to K_MAX candidates (score, box) into workspace. Invalid slots get
// score = -1.0 to mirror flat_scores = where(valid, sel_scores, -1.0).
__global__ __launch_bounds__(256) void nms_kernel(
    const float* __restrict__ rois,      // [N][B][4]  (y1,x1,y2,x2)
    const float* __restrict__ conf,      // [N][B][81]
    const float* __restrict__ deltas,    // [N][B][320]
    float* __restrict__ candScore,       // [N][CAND]
    float* __restrict__ candBox)         // [N][CAND][4]
{
    __shared__ float sy1[B_BOX], sx1[B_BOX], sy2[B_BOX], sx2[B_BOX];
    __shared__ float sarea[B_BOX], swork[B_BOX];
    __shared__ float redV[4];
    __shared__ int   redI[4];

    const int n   = blockIdx.x / N_CLS;
    const int c   = blockIdx.x % N_CLS;
    const int tid = threadIdx.x;

    // --- decode: exact op ordering of the reference, contraction blocked ---
    for (int b = tid; b < B_BOX; b += 256) {
        float4 rr = ((const float4*)rois)[n * B_BOX + b];          // y1,x1,y2,x2
        float4 dd = ((const float4*)deltas)[(n * B_BOX + b) * N_CLS + c];
        float score = conf[((size_t)(n * B_BOX + b)) * C1 + c];

        float w0 = __fadd_rn(__fsub_rn(rr.w, rr.y), 1.0f);   // x2-x1+1
        float h0 = __fadd_rn(__fsub_rn(rr.z, rr.x), 1.0f);   // y2-y1+1
        float x0 = __fadd_rn(rr.y, __fmul_rn(w0, 0.5f));     // w0/2 exact
        float y0 = __fadd_rn(rr.x, __fmul_rn(h0, 0.5f));
        float tx = __fdiv_rn(dd.x, 10.0f);
        float ty = __fdiv_rn(dd.y, 10.0f);
        float tw = __fdiv_rn(dd.z, 5.0f);
        float th = __fdiv_rn(dd.w, 5.0f);
        float cx = __fadd_rn(__fmul_rn(tx, w0), x0);
        float cy = __fadd_rn(__fmul_rn(ty, h0), y0);
        float ww = __fmul_rn(expf(tw), w0);
        float hh = __fmul_rn(expf(th), h0);

        float xx1 = fminf(fmaxf(__fsub_rn(cx, __fmul_rn(0.5f, ww)), 0.0f), 799.0f);
        float yy1 = fminf(fmaxf(__fsub_rn(cy, __fmul_rn(0.5f, hh)), 0.0f), 799.0f);
        float xx2 = fminf(fmaxf(__fadd_rn(cx, __fmul_rn(0.5f, ww)), 0.0f), 799.0f);
        float yy2 = fminf(fmaxf(__fadd_rn(cy, __fmul_rn(0.5f, hh)), 0.0f), 799.0f);

        sy1[b] = yy1; sx1[b] = xx1; sy2[b] = yy2; sx2[b] = xx2;
        sarea[b] = __fmul_rn(__fsub_rn(yy2, yy1), __fsub_rn(xx2, xx1));
        swork[b] = (score > 0.05f) ? score : NEGV;
    }
    __syncthreads();

    float* myScore = candScore + (size_t)n * CAND + c * K_MAX;
    float* myBox   = candBox   + ((size_t)n * CAND + c * K_MAX) * 4;

    for (int k = 0; k < K_MAX; k++) {
        // stable argmax over swork[0..B)
        float v = swork[tid]; int idx = tid;
        for (int b = tid + 256; b < B_BOX; b += 256) {
            float x = swork[b];
            if (x > v) { v = x; idx = b; }   // strict > keeps first occurrence
        }
        blockArgmax(v, idx, redV, redI, tid);

        const bool valid = v > (NEGV * 0.5f);   // values are either scores or exactly NEGV
        if (!valid) {
            // everything exhausted: remaining slots are invalid (score -1)
            for (int k2 = k + tid; k2 < K_MAX; k2 += 256) {
                myScore[k2] = -1.0f;
                myBox[k2 * 4 + 0] = 0.0f; myBox[k2 * 4 + 1] = 0.0f;
                myBox[k2 * 4 + 2] = 0.0f; myBox[k2 * 4 + 3] = 0.0f;
            }
            return;   // uniform across block
        }

        const float by1 = sy1[idx], bx1 = sx1[idx];
        const float by2 = sy2[idx], bx2 = sx2[idx];
        const float bar = sarea[idx];

        if (tid == 0) {
            myScore[k] = v;
            myBox[k * 4 + 0] = by1; myBox[k * 4 + 1] = bx1;
            myBox[k * 4 + 2] = by2; myBox[k * 4 + 3] = bx2;
        }

        // suppress: work = where(iou > 0.5, NEG, work); work[best] = NEG
        for (int b = tid; b < B_BOX; b += 256) {
            float iy1 = fmaxf(by1, sy1[b]);
            float ix1 = fmaxf(bx1, sx1[b]);
            float iy2 = fminf(by2, sy2[b]);
            float ix2 = fminf(bx2, sx2[b]);
            float ih  = fmaxf(__fsub_rn(iy2, iy1), 0.0f);
            float iw  = fmaxf(__fsub_rn(ix2, ix1), 0.0f);
            float inter = __fmul_rn(ih, iw);
            float denom = fmaxf(__fsub_rn(__fadd_rn(bar, sarea[b]), inter), 1e-8f);
            float iou   = __fdiv_rn(inter, denom);
            if (iou > 0.5f) swork[b] = NEGV;
        }
        if (tid == 0) swork[idx] = NEGV;   // same value as any racing suppress write
        __syncthreads();
    }
}

// One block per image: stable top-100 of 8000 candidate scores, then write
// boxes/scores/classes/num_dets with the where(valid, ..., 0) semantics.
__global__ __launch_bounds__(256) void topk_kernel(
    const float* __restrict__ candScore,
    const float* __restrict__ candBox,
    float* __restrict__ out)
{
    __shared__ float s[CAND];
    __shared__ float selV[K_MAX];
    __shared__ int   selI[K_MAX];
    __shared__ float redV[4];
    __shared__ int   redI[4];

    const int n   = blockIdx.x;
    const int tid = threadIdx.x;

    for (int i = tid; i < CAND; i += 256) s[i] = candScore[(size_t)n * CAND + i];
    __syncthreads();

    for (int k = 0; k < K_MAX; k++) {
        float v = s[tid]; int idx = tid;
        for (int b = tid + 256; b < CAND; b += 256) {
            float x = s[b];
            if (x > v) { v = x; idx = b; }
        }
        blockArgmax(v, idx, redV, redI, tid);
        if (tid == 0) { selV[k] = v; selI[k] = idx; s[idx] = -3.0e38f; }
        __syncthreads();
    }

    if (tid < K_MAX) {
        const int   g     = selI[tid];
        const float v     = selV[tid];
        const bool  valid = v > 0.0f;   // valid candidates have score > 0.05; invalid are -1
        float b0 = 0.0f, b1 = 0.0f, b2 = 0.0f, b3 = 0.0f;
        if (valid) {
            const float* bx = candBox + ((size_t)n * CAND + g) * 4;
            b0 = bx[0]; b1 = bx[1]; b2 = bx[2]; b3 = bx[3];
        }
        float* boxes = out;                         // [N][K][4]
        boxes[(size_t)n * K_MAX * 4 + tid * 4 + 0] = b0;
        boxes[(size_t)n * K_MAX * 4 + tid * 4 + 1] = b1;
        boxes[(size_t)n * K_MAX * 4 + tid * 4 + 2] = b2;
        boxes[(size_t)n * K_MAX * 4 + tid * 4 + 3] = b3;
        out[N_IMG * K_MAX * 4 + n * K_MAX + tid] = valid ? v : 0.0f;                 // scores
        out[N_IMG * K_MAX * 5 + n * K_MAX + tid] = valid ? (float)(g / K_MAX) : 0.0f; // classes
    }
    if (tid == 0) {
        int cnt = 0;
        for (int k = 0; k < K_MAX; k++) cnt += (selV[k] > 0.0f) ? 1 : 0;
        out[N_IMG * K_MAX * 6 + n] = (float)cnt;   // num_dets
    }
}

extern "C" void kernel_launch(void* const* d_in, const int* in_sizes, int n_in,
                              void* d_out, int out_size, void* d_ws, size_t ws_size,
                              hipStream_t stream) {
    const float* rois   = (const float*)d_in[0];   // [8][1000][4]
    const float* conf   = (const float*)d_in[1];   // [8][1000][81]
    const float* deltas = (const float*)d_in[2];   // [8][1000][320]
    float* out = (float*)d_out;                    // 36808 floats
    float* ws  = (float*)d_ws;

    float* candScore = ws;                          // N*CAND        = 64000 floats
    float* candBox   = ws + (size_t)N_IMG * CAND;   // N*CAND*4      = 256000 floats

    nms_kernel<<<N_IMG * N_CLS, 256, 0, stream>>>(rois, conf, deltas, candScore, candBox);
    topk_kernel<<<N_IMG, 256, 0, stream>>>(candScore, candBox, out);

    // Output 4: rois passthrough (offset 4808 floats)
    hipMemcpyAsync(out + 4808, rois,
                   (size_t)N_IMG * B_BOX * 4 * sizeof(float),
                   hipMemcpyDeviceToDevice, stream);
}

// Round 2
// 359.250 us; speedup vs baseline: 1.4837x; 1.4837x over previous
//
#include <hip/hip_runtime.h>
#include <cstddef>

#define N_IMG 8
#define B_BOX 1000
#define N_CLS 80
#define C1    81
#define K_MAX 100
#define CAND  (N_CLS * K_MAX)   // 8000
#define NEGV  (-1.0e10f)
#define NSLOT 16                // 16*64 = 1024 >= 1000 boxes per lane-ownership

// ---------------------------------------------------------------------------
// NMS: one WAVE (64 threads) per (image, class). Lane L owns boxes
// b = L + i*64, i in [0,16). All mutable state (work scores) lives in
// registers; box coords live in registers (for the IoU pass) AND in LDS
// (for uniform-address broadcast of the selected box). No __syncthreads in
// the main loop.
// ---------------------------------------------------------------------------
__global__ __launch_bounds__(64) void nms_kernel(
    const float* __restrict__ rois,      // [N][B][4]  (y1,x1,y2,x2)
    const float* __restrict__ conf,      // [N][B][81]
    const float* __restrict__ deltas,    // [N][B][320]
    float* __restrict__ candScore,       // [N][CAND]
    float* __restrict__ candBox)         // [N][CAND][4]
{
    __shared__ float sy1[B_BOX], sx1[B_BOX], sy2[B_BOX], sx2[B_BOX], sar[B_BOX];

    const int n    = blockIdx.x / N_CLS;
    const int c    = blockIdx.x % N_CLS;
    const int lane = threadIdx.x;

    float ry1[NSLOT], rx1[NSLOT], ry2[NSLOT], rx2[NSLOT], rar[NSLOT], rwk[NSLOT];

    // --- decode (identical FP ordering to the verified round-1 kernel) ---
    #pragma unroll
    for (int i = 0; i < NSLOT; i++) {
        const int b = lane + i * 64;
        if (b < B_BOX) {
            float4 rr = ((const float4*)rois)[n * B_BOX + b];              // y1,x1,y2,x2
            float4 dd = ((const float4*)deltas)[(n * B_BOX + b) * N_CLS + c];
            float score = conf[((size_t)(n * B_BOX + b)) * C1 + c];

            float w0 = __fadd_rn(__fsub_rn(rr.w, rr.y), 1.0f);
            float h0 = __fadd_rn(__fsub_rn(rr.z, rr.x), 1.0f);
            float x0 = __fadd_rn(rr.y, __fmul_rn(w0, 0.5f));
            float y0 = __fadd_rn(rr.x, __fmul_rn(h0, 0.5f));
            float tx = __fdiv_rn(dd.x, 10.0f);
            float ty = __fdiv_rn(dd.y, 10.0f);
            float tw = __fdiv_rn(dd.z, 5.0f);
            float th = __fdiv_rn(dd.w, 5.0f);
            float cx = __fadd_rn(__fmul_rn(tx, w0), x0);
            float cy = __fadd_rn(__fmul_rn(ty, h0), y0);
            float ww = __fmul_rn(expf(tw), w0);
            float hh = __fmul_rn(expf(th), h0);

            float xx1 = fminf(fmaxf(__fsub_rn(cx, __fmul_rn(0.5f, ww)), 0.0f), 799.0f);
            float yy1 = fminf(fmaxf(__fsub_rn(cy, __fmul_rn(0.5f, hh)), 0.0f), 799.0f);
            float xx2 = fminf(fmaxf(__fadd_rn(cx, __fmul_rn(0.5f, ww)), 0.0f), 799.0f);
            float yy2 = fminf(fmaxf(__fadd_rn(cy, __fmul_rn(0.5f, hh)), 0.0f), 799.0f);

            ry1[i] = yy1; rx1[i] = xx1; ry2[i] = yy2; rx2[i] = xx2;
            rar[i] = __fmul_rn(__fsub_rn(yy2, yy1), __fsub_rn(xx2, xx1));
            rwk[i] = (score > 0.05f) ? score : NEGV;

            sy1[b] = yy1; sx1[b] = xx1; sy2[b] = yy2; sx2[b] = xx2; sar[b] = rar[i];
        } else {
            ry1[i] = 0.0f; rx1[i] = 0.0f; ry2[i] = 0.0f; rx2[i] = 0.0f;
            rar[i] = 0.0f; rwk[i] = NEGV;   // pad slots never win (tie -> min idx)
        }
    }
    __syncthreads();   // single wave: just orders LDS writes before reads

    float* myScore = candScore + (size_t)n * CAND + c * K_MAX;
    float* myBox   = candBox   + ((size_t)n * CAND + c * K_MAX) * 4;

    int k = 0;
    for (; k < K_MAX; k++) {
        // local stable argmax over owned slots (strict > keeps smallest b)
        float v = rwk[0]; int idx = lane;
        #pragma unroll
        for (int i = 1; i < NSLOT; i++) {
            if (rwk[i] > v) { v = rwk[i]; idx = lane + i * 64; }
        }
        // wave butterfly: max value, tie -> min index; converges on all lanes
        #pragma unroll
        for (int off = 1; off < 64; off <<= 1) {
            float ov = __shfl_xor(v, off);
            int   oi = __shfl_xor(idx, off);
            if (ov > v || (ov == v && oi < idx)) { v = ov; idx = oi; }
        }

        if (!(v > NEGV * 0.5f)) break;   // exhausted (uniform)

        // broadcast best box: uniform-address LDS reads (HW broadcast)
        const float by1 = sy1[idx], bx1 = sx1[idx];
        const float by2 = sy2[idx], bx2 = sx2[idx];
        const float bar = sar[idx];

        if (lane == 0) {
            myScore[k] = v;
            myBox[4 * k + 0] = by1; myBox[4 * k + 1] = bx1;
            myBox[4 * k + 2] = by2; myBox[4 * k + 3] = bx2;
        }

        // suppress on registers; explicit clear of the selected slot
        #pragma unroll
        for (int i = 0; i < NSLOT; i++) {
            const int b = lane + i * 64;
            float iy1 = fmaxf(by1, ry1[i]);
            float ix1 = fmaxf(bx1, rx1[i]);
            float iy2 = fminf(by2, ry2[i]);
            float ix2 = fminf(bx2, rx2[i]);
            float ih  = fmaxf(__fsub_rn(iy2, iy1), 0.0f);
            float iw  = fmaxf(__fsub_rn(ix2, ix1), 0.0f);
            float inter = __fmul_rn(ih, iw);
            float denom = fmaxf(__fsub_rn(__fadd_rn(bar, rar[i]), inter), 1e-8f);
            float iou   = __fdiv_rn(inter, denom);
            if (iou > 0.5f || b == idx) rwk[i] = NEGV;
        }
    }
    // remaining slots invalid: score = -1 (boxes never read when score <= 0)
    for (int k2 = k + lane; k2 < K_MAX; k2 += 64) myScore[k2] = -1.0f;
}

// ---------------------------------------------------------------------------
// Top-K: one WAVE per image. Each class's candidate list is already sorted
// descending (NMS emits sequential argmaxes; -1 tail for invalid), so the
// per-image top-100 is an 80-way merge. Lane L owns classes L and L+64.
// Stable tie rule of lax.top_k (value desc, flat index asc) is preserved:
// once heads reach the -1 tails, min-flat-index = min class head.
// ---------------------------------------------------------------------------
__global__ __launch_bounds__(64) void topk_kernel(
    const float* __restrict__ candScore,
    const float* __restrict__ candBox,
    float* __restrict__ out)
{
    __shared__ float s[CAND];

    const int n    = blockIdx.x;
    const int lane = threadIdx.x;

    for (int i = lane; i < CAND / 4; i += 64)
        ((float4*)s)[i] = ((const float4*)(candScore + (size_t)n * CAND))[i];
    __syncthreads();   // single wave: orders LDS writes

    const int c0 = lane, c1 = lane + 64;
    const bool has1 = (c1 < N_CLS);
    int h0 = 0, h1 = 0;
    int cnt = 0;

    for (int k = 0; k < K_MAX; k++) {
        float v0 = (h0 < K_MAX) ? s[c0 * K_MAX + h0] : -3.0e38f;
        float v1 = (has1 && h1 < K_MAX) ? s[c1 * K_MAX + h1] : -3.0e38f;
        float v; int fi;
        if (v1 > v0) { v = v1; fi = c1 * K_MAX + h1; }   // tie -> c0 (smaller flat idx)
        else         { v = v0; fi = c0 * K_MAX + h0; }

        #pragma unroll
        for (int off = 1; off < 64; off <<= 1) {
            float ov = __shfl_xor(v, off);
            int   oi = __shfl_xor(fi, off);
            if (ov > v || (ov == v && oi < fi)) { v = ov; fi = oi; }
        }
        // winner (v, fi) uniform
        const int wc = fi / K_MAX;
        if (wc == c0)            h0++;
        else if (has1 && wc == c1) h1++;

        const bool valid = v > 0.0f;   // valid scores > 0.05; invalid are -1
        if (lane == 0) {
            float b0 = 0.0f, b1 = 0.0f, b2 = 0.0f, b3 = 0.0f;
            if (valid) {
                const float* bx = candBox + ((size_t)n * CAND + fi) * 4;
                b0 = bx[0]; b1 = bx[1]; b2 = bx[2]; b3 = bx[3];
            }
            out[(size_t)n * K_MAX * 4 + k * 4 + 0] = b0;
            out[(size_t)n * K_MAX * 4 + k * 4 + 1] = b1;
            out[(size_t)n * K_MAX * 4 + k * 4 + 2] = b2;
            out[(size_t)n * K_MAX * 4 + k * 4 + 3] = b3;
            out[N_IMG * K_MAX * 4 + n * K_MAX + k] = valid ? v : 0.0f;           // scores
            out[N_IMG * K_MAX * 5 + n * K_MAX + k] = valid ? (float)wc : 0.0f;   // classes
            if (valid) cnt++;
        }
    }
    if (lane == 0) out[N_IMG * K_MAX * 6 + n] = (float)cnt;   // num_dets
}

extern "C" void kernel_launch(void* const* d_in, const int* in_sizes, int n_in,
                              void* d_out, int out_size, void* d_ws, size_t ws_size,
                              hipStream_t stream) {
    const float* rois   = (const float*)d_in[0];   // [8][1000][4]
    const float* conf   = (const float*)d_in[1];   // [8][1000][81]
    const float* deltas = (const float*)d_in[2];   // [8][1000][320]
    float* out = (float*)d_out;                    // 36808 floats
    float* ws  = (float*)d_ws;

    float* candScore = ws;                          // 8*8000 floats
    float* candBox   = ws + (size_t)N_IMG * CAND;   // 8*8000*4 floats

    nms_kernel<<<N_IMG * N_CLS, 64, 0, stream>>>(rois, conf, deltas, candScore, candBox);
    topk_kernel<<<N_IMG, 64, 0, stream>>>(candScore, candBox, out);

    hipMemcpyAsync(out + 4808, rois,
                   (size_t)N_IMG * B_BOX * 4 * sizeof(float),
                   hipMemcpyDeviceToDevice, stream);
}

// Round 3
// 274.548 us; speedup vs baseline: 1.9414x; 1.3085x over previous
//
#include <hip/hip_runtime.h>
#include <cstddef>

#define N_IMG 8
#define B_BOX 1000
#define N_CLS 80
#define C1    81
#define K_MAX 100
#define CAND  (N_CLS * K_MAX)   // 8000
#define NEGV  (-1.0e10f)
#define NSLOT 16                // boxes per lane (blocked: lane L owns 16L..16L+15)

// ---- DPP wave64 reductions (VALU-latency, no LDS) -------------------------
// row_shr:1/2/4/8 then row_bcast:15, row_bcast:31 leaves full-wave result in
// lane 63. bound_ctrl=false + old=identity keeps OOB lanes neutral.
template <int CTRL>
__device__ __forceinline__ float dpp_fmax_step(float x, float ident) {
    int o = __builtin_amdgcn_update_dpp(__float_as_int(ident), __float_as_int(x),
                                        CTRL, 0xf, 0xf, false);
    return fmaxf(x, __int_as_float(o));
}
__device__ __forceinline__ float wave_max_bcast(float x, float ident) {
    x = dpp_fmax_step<0x111>(x, ident);   // row_shr:1
    x = dpp_fmax_step<0x112>(x, ident);   // row_shr:2
    x = dpp_fmax_step<0x114>(x, ident);   // row_shr:4
    x = dpp_fmax_step<0x118>(x, ident);   // row_shr:8
    x = dpp_fmax_step<0x142>(x, ident);   // row_bcast:15
    x = dpp_fmax_step<0x143>(x, ident);   // row_bcast:31
    return __int_as_float(__builtin_amdgcn_readlane(__float_as_int(x), 63));
}
template <int CTRL>
__device__ __forceinline__ int dpp_imin_step(int x, int ident) {
    int o = __builtin_amdgcn_update_dpp(ident, x, CTRL, 0xf, 0xf, false);
    return (o < x) ? o : x;
}
__device__ __forceinline__ int wave_min_bcast(int x, int ident) {
    x = dpp_imin_step<0x111>(x, ident);
    x = dpp_imin_step<0x112>(x, ident);
    x = dpp_imin_step<0x114>(x, ident);
    x = dpp_imin_step<0x118>(x, ident);
    x = dpp_imin_step<0x142>(x, ident);
    x = dpp_imin_step<0x143>(x, ident);
    return __builtin_amdgcn_readlane(x, 63);
}

// Exact threshold for fl32(a/b) > 0.5 under RNE:  a/b > 0.5 + 2^-25.
// (double)a > (double)b * CMP is exact: 24-bit x 25-bit significands -> <=49 bits.
#define CMP_IOU (0.5 + 0x1p-25)

// ---------------------------------------------------------------------------
// NMS: one wave per (image, class). Blocked ownership so that on score ties,
// lowest ballot lane == lowest global box index (ranges disjoint, increasing).
// ---------------------------------------------------------------------------
__global__ __launch_bounds__(64) void nms_kernel(
    const float* __restrict__ rois,      // [N][B][4]  (y1,x1,y2,x2)
    const float* __restrict__ conf,      // [N][B][81]
    const float* __restrict__ deltas,    // [N][B][320]
    float* __restrict__ candScore,       // [N][CAND]
    float* __restrict__ candBox)         // [N][CAND][4]
{
    __shared__ float4 sbox[B_BOX];       // (yy1, xx1, yy2, xx2)
    __shared__ float  swk[B_BOX];

    const int n    = blockIdx.x / N_CLS;
    const int c    = blockIdx.x % N_CLS;
    const int lane = threadIdx.x;

    // --- decode, coalesced over b (identical FP ordering to verified kernel) ---
    #pragma unroll
    for (int i = 0; i < NSLOT; i++) {
        const int b = lane + i * 64;
        if (b < B_BOX) {
            float4 rr = ((const float4*)rois)[n * B_BOX + b];
            float4 dd = ((const float4*)deltas)[(n * B_BOX + b) * N_CLS + c];
            float score = conf[((size_t)(n * B_BOX + b)) * C1 + c];

            float w0 = __fadd_rn(__fsub_rn(rr.w, rr.y), 1.0f);
            float h0 = __fadd_rn(__fsub_rn(rr.z, rr.x), 1.0f);
            float x0 = __fadd_rn(rr.y, __fmul_rn(w0, 0.5f));
            float y0 = __fadd_rn(rr.x, __fmul_rn(h0, 0.5f));
            float tx = __fdiv_rn(dd.x, 10.0f);
            float ty = __fdiv_rn(dd.y, 10.0f);
            float tw = __fdiv_rn(dd.z, 5.0f);
            float th = __fdiv_rn(dd.w, 5.0f);
            float cx = __fadd_rn(__fmul_rn(tx, w0), x0);
            float cy = __fadd_rn(__fmul_rn(ty, h0), y0);
            float ww = __fmul_rn(expf(tw), w0);
            float hh = __fmul_rn(expf(th), h0);

            float xx1 = fminf(fmaxf(__fsub_rn(cx, __fmul_rn(0.5f, ww)), 0.0f), 799.0f);
            float yy1 = fminf(fmaxf(__fsub_rn(cy, __fmul_rn(0.5f, hh)), 0.0f), 799.0f);
            float xx2 = fminf(fmaxf(__fadd_rn(cx, __fmul_rn(0.5f, ww)), 0.0f), 799.0f);
            float yy2 = fminf(fmaxf(__fadd_rn(cy, __fmul_rn(0.5f, hh)), 0.0f), 799.0f);

            sbox[b] = make_float4(yy1, xx1, yy2, xx2);
            swk[b]  = (score > 0.05f) ? score : NEGV;
        }
    }
    __syncthreads();

    // --- blocked register fill: lane L owns b = 16L + i ---
    float4 rb[NSLOT];
    float  rar[NSLOT], rwk[NSLOT];
    const int base = lane * NSLOT;
    #pragma unroll
    for (int i = 0; i < NSLOT; i++) {
        const int b = base + i;
        if (b < B_BOX) {
            float4 q = sbox[b];
            rb[i]  = q;
            rar[i] = __fmul_rn(__fsub_rn(q.z, q.x), __fsub_rn(q.w, q.y));
            rwk[i] = swk[b];
        } else {
            rb[i]  = make_float4(0.0f, 0.0f, 0.0f, 0.0f);
            rar[i] = 0.0f;
            rwk[i] = NEGV;
        }
    }

    float* myScore = candScore + (size_t)n * CAND + c * K_MAX;
    float* myBox   = candBox   + ((size_t)n * CAND + c * K_MAX) * 4;

    int k = 0;
    for (; k < K_MAX; k++) {
        // local argmax: depth-4 tree, left operand has smaller index -> strict >
        float tv[8]; int ti[8];
        #pragma unroll
        for (int i = 0; i < 8; i++) {
            bool t = rwk[2*i+1] > rwk[2*i];
            tv[i] = t ? rwk[2*i+1] : rwk[2*i];
            ti[i] = t ? (2*i+1) : (2*i);
        }
        #pragma unroll
        for (int i = 0; i < 4; i++) {
            bool t = tv[2*i+1] > tv[2*i];
            tv[i] = t ? tv[2*i+1] : tv[2*i];
            ti[i] = t ? ti[2*i+1] : ti[2*i];
        }
        #pragma unroll
        for (int i = 0; i < 2; i++) {
            bool t = tv[2*i+1] > tv[2*i];
            tv[i] = t ? tv[2*i+1] : tv[2*i];
            ti[i] = t ? ti[2*i+1] : ti[2*i];
        }
        bool t0 = tv[1] > tv[0];
        const float lv = t0 ? tv[1] : tv[0];
        const int   li = base + (t0 ? ti[1] : ti[0]);

        const float M = wave_max_bcast(lv, NEGV);   // SGPR-uniform
        if (!(M > NEGV * 0.5f)) break;              // uniform scalar branch

        unsigned long long mask = __ballot(lv == M);
        const int winner = __ffsll((unsigned long long)mask) - 1;  // lowest lane = lowest box idx
        const int bi     = __builtin_amdgcn_readlane(li, winner);

        const float4 bb  = sbox[bi];   // uniform-address ds_read_b128 (broadcast)
        const float  bar = __fmul_rn(__fsub_rn(bb.z, bb.x), __fsub_rn(bb.w, bb.y));

        if (lane == 0) {
            myScore[k] = M;
            myBox[4*k + 0] = bb.x; myBox[4*k + 1] = bb.y;
            myBox[4*k + 2] = bb.z; myBox[4*k + 3] = bb.w;
        }

        #pragma unroll
        for (int i = 0; i < NSLOT; i++) {
            float iy1 = fmaxf(bb.x, rb[i].x);
            float ix1 = fmaxf(bb.y, rb[i].y);
            float iy2 = fminf(bb.z, rb[i].z);
            float ix2 = fminf(bb.w, rb[i].w);
            float ih  = fmaxf(__fsub_rn(iy2, iy1), 0.0f);
            float iw  = fmaxf(__fsub_rn(ix2, ix1), 0.0f);
            float inter = __fmul_rn(ih, iw);
            float denom = fmaxf(__fsub_rn(__fadd_rn(bar, rar[i]), inter), 1e-8f);
            // exact reformulation of  __fdiv_rn(inter,denom) > 0.5f
            bool sup = ((double)inter > (double)denom * CMP_IOU) || (base + i == bi);
            rwk[i] = sup ? NEGV : rwk[i];
        }
    }
    for (int k2 = k + lane; k2 < K_MAX; k2 += 64) myScore[k2] = -1.0f;
}

// ---------------------------------------------------------------------------
// Top-K: one wave per image; 80-way merge of the per-class sorted lists.
// Lane L holds heads of classes L and L+64. Positive-score ties use a rare
// scalar-branched min-flat-index reduce; ties at M<=0 produce zeroed outputs
// so pick order is irrelevant there.
// ---------------------------------------------------------------------------
__global__ __launch_bounds__(64) void topk_kernel(
    const float* __restrict__ candScore,
    const float* __restrict__ candBox,
    float* __restrict__ out)
{
    __shared__ float s[CAND];

    const int n    = blockIdx.x;
    const int lane = threadIdx.x;

    for (int i = lane; i < CAND / 4; i += 64)
        ((float4*)s)[i] = ((const float4*)(candScore + (size_t)n * CAND))[i];
    __syncthreads();

    const int  c0   = lane, c1 = lane + 64;
    const bool has1 = (c1 < N_CLS);
    int h0 = 0, h1 = 0;

    int k = 0;
    for (; k < K_MAX; k++) {
        float v0 = (h0 < K_MAX) ? s[c0 * K_MAX + h0] : -3.0e38f;
        float v1 = (has1 && h1 < K_MAX) ? s[c1 * K_MAX + h1] : -3.0e38f;
        float lv; int lfi;
        if (v1 > v0) { lv = v1; lfi = c1 * K_MAX + h1; }  // tie -> c0 (smaller flat idx)
        else         { lv = v0; lfi = c0 * K_MAX + h0; }

        const float M = wave_max_bcast(lv, -3.0e38f);
        if (!(M > 0.0f)) break;   // everything remaining is invalid -> zeros

        unsigned long long mask = __ballot(lv == M);
        int fi;
        if (__popcll(mask) == 1) {
            fi = __builtin_amdgcn_readlane(lfi, __ffsll(mask) - 1);
        } else {
            // rare: positive-score tie across classes -> exact min flat index
            int cnd = (lv == M) ? lfi : 0x7fffffff;
            fi = wave_min_bcast(cnd, 0x7fffffff);
        }
        const int wc = fi / K_MAX;
        if (wc == c0) h0++;
        else if (has1 && wc == c1) h1++;

        if (lane == 0) {
            const float* bx = candBox + ((size_t)n * CAND + fi) * 4;
            out[(size_t)n * K_MAX * 4 + 4*k + 0] = bx[0];
            out[(size_t)n * K_MAX * 4 + 4*k + 1] = bx[1];
            out[(size_t)n * K_MAX * 4 + 4*k + 2] = bx[2];
            out[(size_t)n * K_MAX * 4 + 4*k + 3] = bx[3];
            out[N_IMG * K_MAX * 4 + n * K_MAX + k] = M;           // score
            out[N_IMG * K_MAX * 5 + n * K_MAX + k] = (float)wc;   // class
        }
    }
    // zero-fill the invalid tail; num_dets = k
    for (int q = 4*k + lane; q < 4*K_MAX; q += 64)
        out[(size_t)n * K_MAX * 4 + q] = 0.0f;
    for (int q = k + lane; q < K_MAX; q += 64) {
        out[N_IMG * K_MAX * 4 + n * K_MAX + q] = 0.0f;
        out[N_IMG * K_MAX * 5 + n * K_MAX + q] = 0.0f;
    }
    if (lane == 0) out[N_IMG * K_MAX * 6 + n] = (float)k;
}

extern "C" void kernel_launch(void* const* d_in, const int* in_sizes, int n_in,
                              void* d_out, int out_size, void* d_ws, size_t ws_size,
                              hipStream_t stream) {
    const float* rois   = (const float*)d_in[0];   // [8][1000][4]
    const float* conf   = (const float*)d_in[1];   // [8][1000][81]
    const float* deltas = (const float*)d_in[2];   // [8][1000][320]
    float* out = (float*)d_out;                    // 36808 floats
    float* ws  = (float*)d_ws;

    float* candScore = ws;                          // 8*8000 floats
    float* candBox   = ws + (size_t)N_IMG * CAND;   // 8*8000*4 floats

    nms_kernel<<<N_IMG * N_CLS, 64, 0, stream>>>(rois, conf, deltas, candScore, candBox);
    topk_kernel<<<N_IMG, 64, 0, stream>>>(candScore, candBox, out);

    hipMemcpyAsync(out + 4808, rois,
                   (size_t)N_IMG * B_BOX * 4 * sizeof(float),
                   hipMemcpyDeviceToDevice, stream);
}

// Round 4
// 195.808 us; speedup vs baseline: 2.7221x; 1.4021x over previous
//
#include <hip/hip_runtime.h>
#include <cstddef>

#define N_IMG 8
#define B_BOX 1000
#define N_CLS 80
#define C1    81
#define K_MAX 100
#define CAND  (N_CLS * K_MAX)   // 8000

typedef unsigned long long u64;

// Exact threshold for fl32(a/b) > 0.5 under RNE:  a/b > 0.5 + 2^-25.
// (double)a > (double)b * CMP is exact: 24-bit x 25-bit significands <= 49 bits.
#define CMP_IOU (0.5 + 0x1p-25)

// ---- DPP wave64 reductions (verified round 3) -----------------------------
template <int CTRL>
__device__ __forceinline__ float dpp_fmax_step(float x, float ident) {
    int o = __builtin_amdgcn_update_dpp(__float_as_int(ident), __float_as_int(x),
                                        CTRL, 0xf, 0xf, false);
    return fmaxf(x, __int_as_float(o));
}
__device__ __forceinline__ float wave_max_bcast(float x, float ident) {
    x = dpp_fmax_step<0x111>(x, ident);
    x = dpp_fmax_step<0x112>(x, ident);
    x = dpp_fmax_step<0x114>(x, ident);
    x = dpp_fmax_step<0x118>(x, ident);
    x = dpp_fmax_step<0x142>(x, ident);
    x = dpp_fmax_step<0x143>(x, ident);
    return __int_as_float(__builtin_amdgcn_readlane(__float_as_int(x), 63));
}
template <int CTRL>
__device__ __forceinline__ int dpp_imin_step(int x, int ident) {
    int o = __builtin_amdgcn_update_dpp(ident, x, CTRL, 0xf, 0xf, false);
    return (o < x) ? o : x;
}
__device__ __forceinline__ int wave_min_bcast(int x, int ident) {
    x = dpp_imin_step<0x111>(x, ident);
    x = dpp_imin_step<0x112>(x, ident);
    x = dpp_imin_step<0x114>(x, ident);
    x = dpp_imin_step<0x118>(x, ident);
    x = dpp_imin_step<0x142>(x, ident);
    x = dpp_imin_step<0x143>(x, ident);
    return __builtin_amdgcn_readlane(x, 63);
}

__device__ __forceinline__ u64 shfl_xor_u64(u64 x, int m) {
    unsigned lo = (unsigned)__shfl_xor((int)(unsigned)(x & 0xffffffffu), m);
    unsigned hi = (unsigned)__shfl_xor((int)(unsigned)(x >> 32), m);
    return ((u64)hi << 32) | lo;
}

// ---- register bitonic network helpers -------------------------------------
// Layout: lane L holds 16 u64 keys at global positions p = 16L + t (blocked).
// Directions are the standard ascending network with every direction flipped
// -> overall DESCENDING sort.
template <int J>
__device__ __forceinline__ void ice(u64 (&e)[16], int base, int k) {
    #pragma unroll
    for (int t = 0; t < 16; t++) {
        if ((t & J) == 0) {
            const int u_ = t | J;
            bool up = (((base + t) & k) != 0);     // flipped: "ascending" block
            u64 a = e[t], b = e[u_];
            bool sw = up ? (a > b) : (a < b);
            e[t]  = sw ? b : a;
            e[u_] = sw ? a : b;
        }
    }
}
template <int JL>   // cross-lane stage, element distance j = 16*JL
__device__ __forceinline__ void xce(u64 (&e)[16], int lane, int k) {
    bool lower = ((lane & JL) == 0);
    bool up = ((((lane & ~JL) << 4) & k) != 0);    // k >= 32 here, t bits irrelevant
    bool keepMin = (lower == up);
    #pragma unroll
    for (int t = 0; t < 16; t++) {
        u64 o = shfl_xor_u64(e[t], JL);
        u64 mn = (e[t] < o) ? e[t] : o;
        u64 mx = (e[t] < o) ? o : e[t];
        e[t] = keepMin ? mn : mx;
    }
}
__device__ __forceinline__ void ice_all(u64 (&e)[16], int base, int k) {
    ice<8>(e, base, k); ice<4>(e, base, k); ice<2>(e, base, k); ice<1>(e, base, k);
}

// ---------------------------------------------------------------------------
// NMS: one wave per (image, class).
//   phase 1: decode boxes (blocked ownership b = 16*lane + t), build sort keys
//            key = (score_bits << 32) | (1023 - b)   [0 hi-part if score<=0.05]
//   phase 2: bitonic sort keys descending, entirely in registers/shuffles
//   phase 3: reorder boxes into sorted order in LDS
//   phase 4: scan candidates in order vs kept set (2 kept boxes per lane);
//            stop at 100 kept or first invalid key. Greedy scan == reference
//            sequential argmax (scores only ever drop to NEG), ties exact via
//            the composite key. IoU predicate: exact f64 reformulation
//            (verified rounds 2-3).
// ---------------------------------------------------------------------------
__global__ __launch_bounds__(64) void nms_kernel(
    const float* __restrict__ rois,      // [N][B][4]  (y1,x1,y2,x2)
    const float* __restrict__ conf,      // [N][B][81]
    const float* __restrict__ deltas,    // [N][B][320]
    float* __restrict__ candScore,       // [N][CAND]
    float* __restrict__ candBox)         // [N][CAND][4]
{
    __shared__ float4 sbox[1024];        // decoded boxes, by original index b
    __shared__ u64    skeyS[1026];       // sorted keys (+2 pads for prefetch)
    __shared__ float4 sboxS[1026];       // boxes in sorted order (+2 pads)

    const int n    = blockIdx.x / N_CLS;
    const int c    = blockIdx.x % N_CLS;
    const int lane = threadIdx.x;
    const int base = lane * 16;

    const float4 INERT = make_float4(1.0e9f, 1.0e9f, -1.0e9f, -1.0e9f);

    u64 e[16];

    // --- phase 1: decode (identical FP sequence to verified kernels) -------
    #pragma unroll
    for (int t = 0; t < 16; t++) {
        const int b = base + t;
        if (b < B_BOX) {
            float4 rr = ((const float4*)rois)[n * B_BOX + b];
            float4 dd = ((const float4*)deltas)[(n * B_BOX + b) * N_CLS + c];
            float score = conf[((size_t)(n * B_BOX + b)) * C1 + c];

            float w0 = __fadd_rn(__fsub_rn(rr.w, rr.y), 1.0f);
            float h0 = __fadd_rn(__fsub_rn(rr.z, rr.x), 1.0f);
            float x0 = __fadd_rn(rr.y, __fmul_rn(w0, 0.5f));
            float y0 = __fadd_rn(rr.x, __fmul_rn(h0, 0.5f));
            float tx = __fdiv_rn(dd.x, 10.0f);
            float ty = __fdiv_rn(dd.y, 10.0f);
            float tw = __fdiv_rn(dd.z, 5.0f);
            float th = __fdiv_rn(dd.w, 5.0f);
            float cx = __fadd_rn(__fmul_rn(tx, w0), x0);
            float cy = __fadd_rn(__fmul_rn(ty, h0), y0);
            float ww = __fmul_rn(expf(tw), w0);
            float hh = __fmul_rn(expf(th), h0);

            float xx1 = fminf(fmaxf(__fsub_rn(cx, __fmul_rn(0.5f, ww)), 0.0f), 799.0f);
            float yy1 = fminf(fmaxf(__fsub_rn(cy, __fmul_rn(0.5f, hh)), 0.0f), 799.0f);
            float xx2 = fminf(fmaxf(__fadd_rn(cx, __fmul_rn(0.5f, ww)), 0.0f), 799.0f);
            float yy2 = fminf(fmaxf(__fadd_rn(cy, __fmul_rn(0.5f, hh)), 0.0f), 799.0f);

            sbox[b] = make_float4(yy1, xx1, yy2, xx2);
            unsigned sb = (score > 0.05f) ? __float_as_uint(score) : 0u;
            e[t] = ((u64)sb << 32) | (unsigned)(1023 - b);
        } else {
            sbox[b] = INERT;
            e[t] = (u64)(unsigned)(1023 - b);   // hi = 0 -> invalid, sorts last
        }
    }

    // --- phase 2: bitonic sort, descending, 55 substages --------------------
    ice<1>(e, base, 2);
    ice<2>(e, base, 4);  ice<1>(e, base, 4);
    ice<4>(e, base, 8);  ice<2>(e, base, 8);  ice<1>(e, base, 8);
    ice_all(e, base, 16);
    xce<1>(e, lane, 32);  ice_all(e, base, 32);
    xce<2>(e, lane, 64);  xce<1>(e, lane, 64);  ice_all(e, base, 64);
    xce<4>(e, lane, 128); xce<2>(e, lane, 128); xce<1>(e, lane, 128); ice_all(e, base, 128);
    xce<8>(e, lane, 256); xce<4>(e, lane, 256); xce<2>(e, lane, 256); xce<1>(e, lane, 256);
    ice_all(e, base, 256);
    xce<16>(e, lane, 512); xce<8>(e, lane, 512); xce<4>(e, lane, 512); xce<2>(e, lane, 512);
    xce<1>(e, lane, 512);  ice_all(e, base, 512);
    xce<32>(e, lane, 1024); xce<16>(e, lane, 1024); xce<8>(e, lane, 1024);
    xce<4>(e, lane, 1024);  xce<2>(e, lane, 1024);  xce<1>(e, lane, 1024);
    ice_all(e, base, 1024);

    #pragma unroll
    for (int t = 0; t < 16; t++) skeyS[base + t] = e[t];
    if (lane < 2) { skeyS[1024 + lane] = 0; sboxS[1024 + lane] = INERT; }
    __syncthreads();

    // --- phase 3: boxes into sorted order -----------------------------------
    for (int p = lane; p < 1024; p += 64) {
        u64 key = skeyS[p];
        int b = 1023 - (int)(unsigned)(key & 0xffffffffu);
        sboxS[p] = sbox[b];
    }
    __syncthreads();

    // --- phase 4: greedy scan ----------------------------------------------
    float* myScore = candScore + (size_t)n * CAND + c * K_MAX;
    float* myBox   = candBox   + ((size_t)n * CAND + c * K_MAX) * 4;

    float4 kb0 = INERT, kb1 = INERT;     // kept boxes (slot0: cnt<64, slot1: cnt>=64)
    float  ka0 = 0.0f,  ka1 = 0.0f;
    int cnt = 0;

    u64    kcur = skeyS[0], knxt = skeyS[1];
    float4 bcur = sboxS[0], bnxt = sboxS[1];

    for (int j = 0; j < 1024; j++) {
        if (!(kcur >> 32)) break;                 // first invalid -> all done
        u64    k2 = skeyS[j + 2];                 // 2-deep uniform prefetch
        float4 b2 = sboxS[j + 2];

        const float4 cb = bcur;
        const float  sc = __uint_as_float((unsigned)(kcur >> 32));
        const float  carea = __fmul_rn(__fsub_rn(cb.z, cb.x), __fsub_rn(cb.w, cb.y));

        // IoU(kept, candidate) for both slots — reference op order/orientation
        float iy1a = fmaxf(kb0.x, cb.x), ix1a = fmaxf(kb0.y, cb.y);
        float iy2a = fminf(kb0.z, cb.z), ix2a = fminf(kb0.w, cb.w);
        float iha  = fmaxf(__fsub_rn(iy2a, iy1a), 0.0f);
        float iwa  = fmaxf(__fsub_rn(ix2a, ix1a), 0.0f);
        float intA = __fmul_rn(iha, iwa);
        float denA = fmaxf(__fsub_rn(__fadd_rn(ka0, carea), intA), 1e-8f);
        bool supA  = (double)intA > (double)denA * CMP_IOU;

        float iy1b = fmaxf(kb1.x, cb.x), ix1b = fmaxf(kb1.y, cb.y);
        float iy2b = fminf(kb1.z, cb.z), ix2b = fminf(kb1.w, cb.w);
        float ihb  = fmaxf(__fsub_rn(iy2b, iy1b), 0.0f);
        float iwb  = fmaxf(__fsub_rn(ix2b, ix1b), 0.0f);
        float intB = __fmul_rn(ihb, iwb);
        float denB = fmaxf(__fsub_rn(__fadd_rn(ka1, carea), intB), 1e-8f);
        bool supB  = (double)intB > (double)denB * CMP_IOU;

        u64 m = __ballot(supA || supB);
        if (m == 0) {
            if (lane == (cnt & 63)) {
                if (cnt < 64) { kb0 = cb; ka0 = carea; }
                else          { kb1 = cb; ka1 = carea; }
                myScore[cnt] = sc;
                ((float4*)myBox)[cnt] = cb;
            }
            cnt++;
            if (cnt >= K_MAX) break;
        }
        kcur = knxt; knxt = k2;
        bcur = bnxt; bnxt = b2;
    }
    for (int q = cnt + lane; q < K_MAX; q += 64) myScore[q] = -1.0f;
}

// ---------------------------------------------------------------------------
// Top-K: one wave per image. 80-way merge of per-class descending lists with
// one-ahead register prefetch of each head's successor (reload latency hidden
// across iterations). Selections logged to LDS; boxes gathered in a parallel
// epilogue. Tie semantics of lax.top_k preserved (value desc, flat idx asc).
// ---------------------------------------------------------------------------
__global__ __launch_bounds__(64) void topk_kernel(
    const float* __restrict__ candScore,
    const float* __restrict__ candBox,
    float* __restrict__ out)
{
    __shared__ float selV[K_MAX];
    __shared__ int   selFi[K_MAX];

    const int n    = blockIdx.x;
    const int lane = threadIdx.x;
    const float SENT = -3.0e38f;
    const float* S = candScore + (size_t)n * CAND;

    const int  c0   = lane;
    const int  c1   = lane + 64;
    const bool has1 = (c1 < N_CLS);

    int h0 = 0, h1 = 0;
    float cur0 = S[c0 * K_MAX + 0];
    float nxt0 = S[c0 * K_MAX + 1];
    float cur1 = has1 ? S[c1 * K_MAX + 0] : SENT;
    float nxt1 = has1 ? S[c1 * K_MAX + 1] : SENT;

    int K = 0;
    for (int k = 0; k < K_MAX; k++) {
        float lv; int lfi;
        if (cur1 > cur0) { lv = cur1; lfi = c1 * K_MAX + h1; }   // tie -> c0 (smaller flat)
        else             { lv = cur0; lfi = c0 * K_MAX + h0; }

        float M = wave_max_bcast(lv, SENT);
        if (!(M > 0.0f)) break;    // remaining entries invalid -> zero-fill tail

        u64 m = __ballot(lv == M);
        int fi;
        if (__popcll(m) == 1) {
            fi = __builtin_amdgcn_readlane(lfi, __ffsll(m) - 1);
        } else {
            int cnd = (lv == M) ? lfi : 0x7fffffff;   // exact min flat index on ties
            fi = wave_min_bcast(cnd, 0x7fffffff);
        }

        if (fi == c0 * K_MAX + h0) {
            h0++; cur0 = nxt0;
            nxt0 = (h0 + 1 < K_MAX) ? S[c0 * K_MAX + h0 + 1] : SENT;
        } else if (has1 && fi == c1 * K_MAX + h1) {
            h1++; cur1 = nxt1;
            nxt1 = (h1 + 1 < K_MAX) ? S[c1 * K_MAX + h1 + 1] : SENT;
        }

        if (lane == 0) { selV[k] = M; selFi[k] = fi; }
        K++;
    }
    __syncthreads();

    for (int q = lane; q < K_MAX; q += 64) {
        if (q < K) {
            int   fi = selFi[q];
            float v  = selV[q];
            float4 bx = *((const float4*)(candBox + ((size_t)n * CAND + fi) * 4));
            ((float4*)out)[n * K_MAX + q] = bx;
            out[N_IMG * K_MAX * 4 + n * K_MAX + q] = v;
            out[N_IMG * K_MAX * 5 + n * K_MAX + q] = (float)(fi / K_MAX);
        } else {
            ((float4*)out)[n * K_MAX + q] = make_float4(0.0f, 0.0f, 0.0f, 0.0f);
            out[N_IMG * K_MAX * 4 + n * K_MAX + q] = 0.0f;
            out[N_IMG * K_MAX * 5 + n * K_MAX + q] = 0.0f;
        }
    }
    if (lane == 0) out[N_IMG * K_MAX * 6 + n] = (float)K;
}

extern "C" void kernel_launch(void* const* d_in, const int* in_sizes, int n_in,
                              void* d_out, int out_size, void* d_ws, size_t ws_size,
                              hipStream_t stream) {
    const float* rois   = (const float*)d_in[0];   // [8][1000][4]
    const float* conf   = (const float*)d_in[1];   // [8][1000][81]
    const float* deltas = (const float*)d_in[2];   // [8][1000][320]
    float* out = (float*)d_out;                    // 36808 floats
    float* ws  = (float*)d_ws;

    float* candScore = ws;                          // 8*8000 floats
    float* candBox   = ws + (size_t)N_IMG * CAND;   // 8*8000*4 floats

    nms_kernel<<<N_IMG * N_CLS, 64, 0, stream>>>(rois, conf, deltas, candScore, candBox);
    topk_kernel<<<N_IMG, 64, 0, stream>>>(candScore, candBox, out);

    hipMemcpyAsync(out + 4808, rois,
                   (size_t)N_IMG * B_BOX * 4 * sizeof(float),
                   hipMemcpyDeviceToDevice, stream);
}